// Round 1
// 697.427 us; speedup vs baseline: 1.1700x; 1.1700x over previous
//
#include <hip/hip_runtime.h>

// Problem constants (IcoUpSampleMaxIndexLayer)
#define NB    16      // batch
#define CIN   256
#define COUT  128
#define VRAW  10242
#define NVERT 40962
#define QSZ   10241   // NVERT split into 4 quarters per row (last = 10239)

typedef __attribute__((ext_vector_type(8))) short short8;
typedef __attribute__((ext_vector_type(4))) float floatx4;
// float4 with relaxed (4B) alignment: VRAW=10242 makes row bases only 8B-aligned;
// gfx950 global_load_dwordx4 only needs dword alignment.
typedef float f4u __attribute__((ext_vector_type(4), aligned(4)));

__device__ inline unsigned short f2bf(float f) {
    unsigned u = __builtin_bit_cast(unsigned, f);
    u += 0x7fffu + ((u >> 16) & 1u);   // RNE
    return (unsigned short)(u >> 16);
}

// ---- Kernel 0: convert W (128x256 fp32) to bf16 ----
__global__ __launch_bounds__(256) void convw_kernel(const float* __restrict__ W,
                                                    unsigned short* __restrict__ Wbf) {
    int i = blockIdx.x * 256 + threadIdx.x;   // 32768 elements
    Wbf[i] = f2bf(W[i]);
}

// ---- Kernel 0b: T16[v*8+k] = up[down[v]*7+k] (u16; NVERT<65536) ----
// Collapses the dependent down->up gather chain into one coalesced 16B load per v.
__global__ __launch_bounds__(256) void prep_kernel(const int* __restrict__ up,
                                                   const int* __restrict__ down,
                                                   unsigned short* __restrict__ T16) {
    int idx = blockIdx.x * 256 + threadIdx.x;   // VRAW*8
    if (idx >= VRAW * 8) return;
    int v = idx >> 3;
    int k = idx & 7;
    if (k > 6) k = 6;          // pad slot (k==7 never selected; keep read in-bounds)
    T16[idx] = (unsigned short)up[down[v] * 7 + k];
}

// ---- Kernel 1: h[b,o,v] = sum_c W[o,c] x[b,c,v] + bias[o] ----
// Block 256 thr = 4 waves, tile 128o x 128v, K chunked by 64.
// x chunk staged in LDS as [v][c] bf16 via coalesced float4 loads + in-reg 4x4
// transpose; XOR swizzle on 8B c-groups kills the stride-128B bank conflict.
#define KC 64
#define VT 128
__global__ __launch_bounds__(256) void gemm_kernel(const float* __restrict__ x,
                                                   const unsigned short* __restrict__ Wbf,
                                                   const float* __restrict__ bias,
                                                   float* __restrict__ h) {
    __shared__ unsigned short xt[VT * KC];   // 16 KB, swizzled [v][c]
    const int b    = blockIdx.y;
    const int v0   = blockIdx.x * VT;
    const int tid  = threadIdx.x;
    const int wv   = tid >> 6;
    const int lane = tid & 63;
    const int mn   = lane & 15;   // A-row (o) / B-col (v) within 16-tile
    const int q    = lane >> 4;   // quad
    const int ow   = (wv & 1) * 64;    // wave o base
    const int vwl  = (wv >> 1) * 64;   // wave v base (block-local)

    floatx4 acc[4][4];
#pragma unroll
    for (int ot = 0; ot < 4; ot++)
#pragma unroll
        for (int vt = 0; vt < 4; vt++) acc[ot][vt] = (floatx4)0.f;

    for (int c0 = 0; c0 < CIN; c0 += KC) {
        // ---- stage: 64c x 128v fp32 -> bf16 LDS [v][c] ----
#pragma unroll
        for (int i = 0; i < 2; i++) {
            const int tile  = tid + i * 256;   // 512 micro-tiles of 4c x 4v
            const int cg    = tile >> 5;       // 0..15
            const int vg    = tile & 31;       // 0..31
            const int vglob = v0 + vg * 4;
            const float* xp = x + ((size_t)b * CIN + c0 + cg * 4) * VRAW + vglob;
            float vals[4][4];
            if (vglob + 3 < VRAW) {
#pragma unroll
                for (int cc = 0; cc < 4; cc++) {
                    f4u rv = *(const f4u*)(xp + (size_t)cc * VRAW);
                    vals[cc][0] = rv.x; vals[cc][1] = rv.y;
                    vals[cc][2] = rv.z; vals[cc][3] = rv.w;
                }
            } else {
#pragma unroll
                for (int cc = 0; cc < 4; cc++)
#pragma unroll
                    for (int jj = 0; jj < 4; jj++)
                        vals[cc][jj] = (vglob + jj < VRAW) ? xp[(size_t)cc * VRAW + jj] : 0.f;
            }
            const int swbase = (cg ^ ((vg & 7) << 1)) << 2;   // swizzled u16 col base
#pragma unroll
            for (int jj = 0; jj < 4; jj++) {
                const int vloc = vg * 4 + jj;
                unsigned long long pk =
                      (unsigned long long)f2bf(vals[0][jj])
                    | ((unsigned long long)f2bf(vals[1][jj]) << 16)
                    | ((unsigned long long)f2bf(vals[2][jj]) << 32)
                    | ((unsigned long long)f2bf(vals[3][jj]) << 48);
                *(unsigned long long*)&xt[vloc * KC + swbase] = pk;   // ds_write_b64
            }
        }
        __syncthreads();

        // ---- compute: 2 kk-steps x (4 ot x 4 vt) MFMAs ----
#pragma unroll
        for (int kk = 0; kk < 2; kk++) {
            short8 bfrag[4];
#pragma unroll
            for (int vt = 0; vt < 4; vt++) {
                const int vloc = vwl + vt * 16 + mn;
                const int cqb  = kk * 8 + q * 2;                    // (kk*32+q*8)>>2, even
                const int cq   = cqb ^ (((vloc >> 2) & 7) << 1);    // even -> 16B stays contiguous
                bfrag[vt] = *(const short8*)&xt[vloc * KC + (cq << 2)];  // ds_read_b128
            }
#pragma unroll
            for (int ot = 0; ot < 4; ot++) {
                const short8 afrag = *(const short8*)(Wbf + (size_t)(ow + ot * 16 + mn) * CIN
                                                      + c0 + kk * 32 + q * 8);
#pragma unroll
                for (int vt = 0; vt < 4; vt++)
                    acc[ot][vt] = __builtin_amdgcn_mfma_f32_16x16x32_bf16(afrag, bfrag[vt], acc[ot][vt], 0, 0, 0);
            }
        }
        __syncthreads();
    }

#pragma unroll
    for (int ot = 0; ot < 4; ot++) {
#pragma unroll
        for (int r = 0; r < 4; r++) {
            const int o  = ow + ot * 16 + q * 4 + r;   // C/D: row = quad*4 + reg
            const float bi = bias[o];
#pragma unroll
            for (int vt = 0; vt < 4; vt++) {
                const int v = v0 + vwl + vt * 16 + mn;
                if (v < VRAW) h[((size_t)b * COUT + o) * VRAW + v] = acc[ot][vt][r] + bi;
            }
        }
    }
}

// ---- Kernel 2: dedup (max v wins) + full coalesced y write ----
// 4 blocks per row (quarter = 10241 u32 stamps = 40KB LDS), native ds_max_u32.
// blockIdx swizzled so a row's 4 quarters share one XCD's L2 (mpi/T16/h reuse).
__global__ __launch_bounds__(1024, 8) void scatter_kernel(const unsigned short* __restrict__ T16,
                                                          const int* __restrict__ mpi,
                                                          const float* __restrict__ h,
                                                          float* __restrict__ y) {
    __shared__ __align__(16) unsigned st[QSZ];   // 40964 B
    const int bid = blockIdx.x;
    const int x8  = bid & 7;            // XCD (round-robin dispatch heuristic)
    const int j   = bid >> 3;           // 0..1023
    const int r   = x8 * 256 + (j >> 2);
    const int qi  = j & 3;
    const int tbase = qi * QSZ;
    const int qlen  = min(QSZ, NVERT - tbase);
    const int tid   = threadIdx.x;

    uint4* st4 = (uint4*)st;
    const uint4 z4 = make_uint4(0u, 0u, 0u, 0u);
    st4[tid] = z4;
    st4[tid + 1024] = z4;
    if (tid < 512) st4[tid + 2048] = z4;   // 2560 uint4 = 10240
    if (tid == 0) st[10240] = 0u;
    __syncthreads();

    const int* mpiRow = mpi + (size_t)r * VRAW;
#pragma unroll 2
    for (int it = 0; it < 10; it++) {          // 10*1024 = 10240
        const int v = tid + it * 1024;
        const int k = mpiRow[v];
        const uint4 tt = *(const uint4*)(T16 + (size_t)v * 8);   // 8 candidates, 16B coalesced
        const unsigned w0 = (k & 2) ? tt.y : tt.x;
        const unsigned w1 = (k & 2) ? tt.w : tt.z;
        const unsigned wsel = (k & 4) ? w1 : w0;
        const unsigned t = (wsel >> ((k & 1) * 16)) & 0xffffu;
        const unsigned lt = t - (unsigned)tbase;
        if (lt < (unsigned)qlen) atomicMax(&st[lt], (unsigned)(v + 1));
    }
    if (tid < 2) {                              // v = 10240, 10241
        const int v = 10240 + tid;
        const int k = mpiRow[v];
        const uint4 tt = *(const uint4*)(T16 + (size_t)v * 8);
        const unsigned w0 = (k & 2) ? tt.y : tt.x;
        const unsigned w1 = (k & 2) ? tt.w : tt.z;
        const unsigned wsel = (k & 4) ? w1 : w0;
        const unsigned t = (wsel >> ((k & 1) * 16)) & 0xffffu;
        const unsigned lt = t - (unsigned)tbase;
        if (lt < (unsigned)qlen) atomicMax(&st[lt], (unsigned)(v + 1));
    }
    __syncthreads();

    const float* hRow = h + (size_t)r * VRAW;
    float* yRow = y + (size_t)r * NVERT + tbase;
#pragma unroll
    for (int i2 = 0; i2 < 2; i2++) {           // i < 2048: 4i+3 <= 8195 < qlen always
        const int i = tid + i2 * 1024;
        const uint4 s4 = st4[i];
        f4u out;
        out.x = s4.x ? hRow[s4.x - 1u] : 0.f;
        out.y = s4.y ? hRow[s4.y - 1u] : 0.f;
        out.z = s4.z ? hRow[s4.z - 1u] : 0.f;
        out.w = s4.w ? hRow[s4.w - 1u] : 0.f;
        *(f4u*)(yRow + 4 * i) = out;
    }
    {
        const int i = tid + 2048;
        if (4 * i + 3 < qlen) {
            const uint4 s4 = st4[i];
            f4u out;
            out.x = s4.x ? hRow[s4.x - 1u] : 0.f;
            out.y = s4.y ? hRow[s4.y - 1u] : 0.f;
            out.z = s4.z ? hRow[s4.z - 1u] : 0.f;
            out.w = s4.w ? hRow[s4.w - 1u] : 0.f;
            *(f4u*)(yRow + 4 * i) = out;
        }
    }
    const int base = qlen & ~3;
    if (tid < qlen - base) {
        const int lt = base + tid;
        const unsigned s = st[lt];
        yRow[lt] = s ? hRow[s - 1u] : 0.f;
    }
}

extern "C" void kernel_launch(void* const* d_in, const int* in_sizes, int n_in,
                              void* d_out, int out_size, void* d_ws, size_t ws_size,
                              hipStream_t stream) {
    const float* x    = (const float*)d_in[0];
    const float* W    = (const float*)d_in[1];
    const float* bias = (const float*)d_in[2];
    const int*   up   = (const int*)d_in[3];   // (NVERT, 7)
    const int*   down = (const int*)d_in[4];   // (VRAW,)
    const int*   mpi  = (const int*)d_in[5];   // (NB, COUT, VRAW)
    float* y = (float*)d_out;

    // ws layout: [0,64KB) Wbf bf16 | h fp32 (NB*COUT*VRAW) | T16 u16 (VRAW*8)
    unsigned short* Wbf = (unsigned short*)d_ws;
    float* h = (float*)((char*)d_ws + 65536);
    unsigned short* T16 = (unsigned short*)((char*)d_ws + 65536 + (size_t)NB * COUT * VRAW * 4);

    convw_kernel<<<COUT * CIN / 256, 256, 0, stream>>>(W, Wbf);
    prep_kernel<<<(VRAW * 8 + 255) / 256, 256, 0, stream>>>(up, down, T16);

    dim3 ggrid((VRAW + VT - 1) / VT, NB);
    gemm_kernel<<<ggrid, 256, 0, stream>>>(x, Wbf, bias, h);

    scatter_kernel<<<NB * COUT * 4, 1024, 0, stream>>>(T16, mpi, h, y);
}

// Round 2
// 690.682 us; speedup vs baseline: 1.1814x; 1.0098x over previous
//
#include <hip/hip_runtime.h>

// Problem constants (IcoUpSampleMaxIndexLayer)
#define NB    16      // batch
#define CIN   256
#define COUT  128
#define VRAW  10242
#define NVERT 40962
#define QSZ   10241   // NVERT split into 4 quarters per row (last = 10239)
#define NROW  (NB * COUT)   // 2048

typedef __attribute__((ext_vector_type(8))) short short8;
typedef __attribute__((ext_vector_type(4))) float floatx4;
// float4 with relaxed (4B) alignment: VRAW=10242 makes row bases only 8B-aligned;
// gfx950 global_load_dwordx4 only needs dword alignment.
typedef float f4u __attribute__((ext_vector_type(4), aligned(4)));

__device__ inline unsigned short f2bf(float f) {
    unsigned u = __builtin_bit_cast(unsigned, f);
    u += 0x7fffu + ((u >> 16) & 1u);   // RNE
    return (unsigned short)(u >> 16);
}

// ---- Kernel 0: convert W (128x256 fp32) to bf16 ----
__global__ __launch_bounds__(256) void convw_kernel(const float* __restrict__ W,
                                                    unsigned short* __restrict__ Wbf) {
    int i = blockIdx.x * 256 + threadIdx.x;   // 32768 elements
    Wbf[i] = f2bf(W[i]);
}

// ---- Kernel 0b: T16[v*8+k] = up[down[v]*7+k] (u16; NVERT<65536) ----
__global__ __launch_bounds__(256) void prep_kernel(const int* __restrict__ up,
                                                   const int* __restrict__ down,
                                                   unsigned short* __restrict__ T16) {
    int idx = blockIdx.x * 256 + threadIdx.x;   // VRAW*8
    if (idx >= VRAW * 8) return;
    int v = idx >> 3;
    int k = idx & 7;
    if (k > 6) k = 6;          // pad slot (k==7 never selected; keep read in-bounds)
    T16[idx] = (unsigned short)up[down[v] * 7 + k];
}

// ---- Kernel 0c: resolve targets once per (r,v): tgt16[r][v] = T16[v*8 + mpi[r][v]] ----
// Streaming: mpi read 84MB coalesced, T16 gathers L2-hot (160KB), tgt write 42MB.
// Removes the select chain + mpi re-reads from the scatter's hot loop.
__global__ __launch_bounds__(256) void tgt_kernel(const int* __restrict__ mpi,
                                                  const unsigned short* __restrict__ T16,
                                                  unsigned* __restrict__ tgt32) {
    const int r  = blockIdx.y;
    const int vp = blockIdx.x * 256 + threadIdx.x;   // pair index
    if (vp >= VRAW / 2) return;
    const int2 kk = *(const int2*)(mpi + (size_t)r * VRAW + 2 * (size_t)vp);
    const unsigned t0 = T16[(2 * vp)     * 8 + kk.x];   // k in [0,7)
    const unsigned t1 = T16[(2 * vp + 1) * 8 + kk.y];
    tgt32[(size_t)r * (VRAW / 2) + vp] = t0 | (t1 << 16);
}

// ---- Kernel 1: h[b,o,v] = sum_c W[o,c] x[b,c,v] + bias[o] ---- (unchanged)
#define KC 64
#define VT 128
__global__ __launch_bounds__(256) void gemm_kernel(const float* __restrict__ x,
                                                   const unsigned short* __restrict__ Wbf,
                                                   const float* __restrict__ bias,
                                                   float* __restrict__ h) {
    __shared__ unsigned short xt[VT * KC];   // 16 KB, swizzled [v][c]
    const int b    = blockIdx.y;
    const int v0   = blockIdx.x * VT;
    const int tid  = threadIdx.x;
    const int wv   = tid >> 6;
    const int lane = tid & 63;
    const int mn   = lane & 15;
    const int q    = lane >> 4;
    const int ow   = (wv & 1) * 64;
    const int vwl  = (wv >> 1) * 64;

    floatx4 acc[4][4];
#pragma unroll
    for (int ot = 0; ot < 4; ot++)
#pragma unroll
        for (int vt = 0; vt < 4; vt++) acc[ot][vt] = (floatx4)0.f;

    for (int c0 = 0; c0 < CIN; c0 += KC) {
#pragma unroll
        for (int i = 0; i < 2; i++) {
            const int tile  = tid + i * 256;
            const int cg    = tile >> 5;
            const int vg    = tile & 31;
            const int vglob = v0 + vg * 4;
            const float* xp = x + ((size_t)b * CIN + c0 + cg * 4) * VRAW + vglob;
            float vals[4][4];
            if (vglob + 3 < VRAW) {
#pragma unroll
                for (int cc = 0; cc < 4; cc++) {
                    f4u rv = *(const f4u*)(xp + (size_t)cc * VRAW);
                    vals[cc][0] = rv.x; vals[cc][1] = rv.y;
                    vals[cc][2] = rv.z; vals[cc][3] = rv.w;
                }
            } else {
#pragma unroll
                for (int cc = 0; cc < 4; cc++)
#pragma unroll
                    for (int jj = 0; jj < 4; jj++)
                        vals[cc][jj] = (vglob + jj < VRAW) ? xp[(size_t)cc * VRAW + jj] : 0.f;
            }
            const int swbase = (cg ^ ((vg & 7) << 1)) << 2;
#pragma unroll
            for (int jj = 0; jj < 4; jj++) {
                const int vloc = vg * 4 + jj;
                unsigned long long pk =
                      (unsigned long long)f2bf(vals[0][jj])
                    | ((unsigned long long)f2bf(vals[1][jj]) << 16)
                    | ((unsigned long long)f2bf(vals[2][jj]) << 32)
                    | ((unsigned long long)f2bf(vals[3][jj]) << 48);
                *(unsigned long long*)&xt[vloc * KC + swbase] = pk;
            }
        }
        __syncthreads();

#pragma unroll
        for (int kk = 0; kk < 2; kk++) {
            short8 bfrag[4];
#pragma unroll
            for (int vt = 0; vt < 4; vt++) {
                const int vloc = vwl + vt * 16 + mn;
                const int cqb  = kk * 8 + q * 2;
                const int cq   = cqb ^ (((vloc >> 2) & 7) << 1);
                bfrag[vt] = *(const short8*)&xt[vloc * KC + (cq << 2)];
            }
#pragma unroll
            for (int ot = 0; ot < 4; ot++) {
                const short8 afrag = *(const short8*)(Wbf + (size_t)(ow + ot * 16 + mn) * CIN
                                                      + c0 + kk * 32 + q * 8);
#pragma unroll
                for (int vt = 0; vt < 4; vt++)
                    acc[ot][vt] = __builtin_amdgcn_mfma_f32_16x16x32_bf16(afrag, bfrag[vt], acc[ot][vt], 0, 0, 0);
            }
        }
        __syncthreads();
    }

#pragma unroll
    for (int ot = 0; ot < 4; ot++) {
#pragma unroll
        for (int r = 0; r < 4; r++) {
            const int o  = ow + ot * 16 + q * 4 + r;
            const float bi = bias[o];
#pragma unroll
            for (int vt = 0; vt < 4; vt++) {
                const int v = v0 + vwl + vt * 16 + mn;
                if (v < VRAW) h[((size_t)b * COUT + o) * VRAW + v] = acc[ot][vt][r] + bi;
            }
        }
    }
}

// ---- Kernel 2: dedup (max v wins) + full coalesced y write ----
// 4 quarter-blocks per row, native ds_max_u32, 512 thr -> 3 blocks/CU (24 waves).
// USE_TGT=1: lean scan over precomputed u16 targets (one u32 = 2 targets).
// USE_TGT=0: fallback (round-1 path) if workspace too small for tgt buffer.
template<int USE_TGT>
__global__ __launch_bounds__(512, 6) void scatter_kernel(const unsigned* __restrict__ tgt32,
                                                         const unsigned short* __restrict__ T16,
                                                         const int* __restrict__ mpi,
                                                         const float* __restrict__ h,
                                                         float* __restrict__ y) {
    __shared__ __align__(16) unsigned st[QSZ];   // 40964 B
    const int bid = blockIdx.x;
    const int x8  = bid & 7;            // XCD (round-robin dispatch heuristic)
    const int j   = bid >> 3;           // 0..1023
    const int r   = x8 * 256 + (j >> 2);
    const int qi  = j & 3;
    const int tbase = qi * QSZ;
    const int qlen  = min(QSZ, NVERT - tbase);
    const int tid   = threadIdx.x;

    uint4* st4 = (uint4*)st;
    const uint4 z4 = make_uint4(0u, 0u, 0u, 0u);
#pragma unroll
    for (int i = 0; i < 5; i++) st4[tid + i * 512] = z4;   // 2560 uint4 = 10240 u32
    if (tid == 0) st[10240] = 0u;
    __syncthreads();

    if (USE_TGT) {
        const unsigned* tRow = tgt32 + (size_t)r * (VRAW / 2);
#pragma unroll
        for (int it = 0; it < 10; it++) {
            const int vp = tid + it * 512;                 // pairs 0..5119
            const unsigned tw = tRow[vp];
            const unsigned lt0 = (tw & 0xffffu) - (unsigned)tbase;
            const unsigned lt1 = (tw >> 16)     - (unsigned)tbase;
            if (lt0 < (unsigned)qlen) atomicMax(&st[lt0], (unsigned)(2 * vp + 1));
            if (lt1 < (unsigned)qlen) atomicMax(&st[lt1], (unsigned)(2 * vp + 2));
        }
        if (tid == 0) {                                    // pair 5120 -> v 10240,10241
            const unsigned tw = tRow[5120];
            const unsigned lt0 = (tw & 0xffffu) - (unsigned)tbase;
            const unsigned lt1 = (tw >> 16)     - (unsigned)tbase;
            if (lt0 < (unsigned)qlen) atomicMax(&st[lt0], 10241u);
            if (lt1 < (unsigned)qlen) atomicMax(&st[lt1], 10242u);
        }
    } else {
        const int* mpiRow = mpi + (size_t)r * VRAW;
#pragma unroll 4
        for (int it = 0; it < 20; it++) {
            const int v = tid + it * 512;
            const int k = mpiRow[v];
            const uint4 tt = *(const uint4*)(T16 + (size_t)v * 8);
            const unsigned w0 = (k & 2) ? tt.y : tt.x;
            const unsigned w1 = (k & 2) ? tt.w : tt.z;
            const unsigned wsel = (k & 4) ? w1 : w0;
            const unsigned t = (wsel >> ((k & 1) * 16)) & 0xffffu;
            const unsigned lt = t - (unsigned)tbase;
            if (lt < (unsigned)qlen) atomicMax(&st[lt], (unsigned)(v + 1));
        }
        if (tid < 2) {
            const int v = 10240 + tid;
            const int k = mpiRow[v];
            const uint4 tt = *(const uint4*)(T16 + (size_t)v * 8);
            const unsigned w0 = (k & 2) ? tt.y : tt.x;
            const unsigned w1 = (k & 2) ? tt.w : tt.z;
            const unsigned wsel = (k & 4) ? w1 : w0;
            const unsigned t = (wsel >> ((k & 1) * 16)) & 0xffffu;
            const unsigned lt = t - (unsigned)tbase;
            if (lt < (unsigned)qlen) atomicMax(&st[lt], (unsigned)(v + 1));
        }
    }
    __syncthreads();

    const float* hRow = h + (size_t)r * VRAW;
    float* yRow = y + (size_t)r * NVERT + tbase;
#pragma unroll
    for (int i2 = 0; i2 < 4; i2++) {           // i < 2048: 4i+3 <= 8191 < qlen always
        const int i = tid + i2 * 512;
        const uint4 s4 = st4[i];
        f4u out;
        out.x = s4.x ? hRow[s4.x - 1u] : 0.f;
        out.y = s4.y ? hRow[s4.y - 1u] : 0.f;
        out.z = s4.z ? hRow[s4.z - 1u] : 0.f;
        out.w = s4.w ? hRow[s4.w - 1u] : 0.f;
        *(f4u*)(yRow + 4 * i) = out;
    }
    {
        const int i = tid + 2048;              // 2048..2559
        if (4 * i + 3 < qlen) {
            const uint4 s4 = st4[i];
            f4u out;
            out.x = s4.x ? hRow[s4.x - 1u] : 0.f;
            out.y = s4.y ? hRow[s4.y - 1u] : 0.f;
            out.z = s4.z ? hRow[s4.z - 1u] : 0.f;
            out.w = s4.w ? hRow[s4.w - 1u] : 0.f;
            *(f4u*)(yRow + 4 * i) = out;
        }
    }
    const int base = qlen & ~3;
    if (tid < qlen - base) {
        const int lt = base + tid;
        const unsigned s = st[lt];
        yRow[lt] = s ? hRow[s - 1u] : 0.f;
    }
}

extern "C" void kernel_launch(void* const* d_in, const int* in_sizes, int n_in,
                              void* d_out, int out_size, void* d_ws, size_t ws_size,
                              hipStream_t stream) {
    const float* x    = (const float*)d_in[0];
    const float* W    = (const float*)d_in[1];
    const float* bias = (const float*)d_in[2];
    const int*   up   = (const int*)d_in[3];   // (NVERT, 7)
    const int*   down = (const int*)d_in[4];   // (VRAW,)
    const int*   mpi  = (const int*)d_in[5];   // (NB, COUT, VRAW)
    float* y = (float*)d_out;

    // ws layout: [0,64KB) Wbf | h fp32 (NROW*VRAW) | T16 u16 (VRAW*8) | tgt u16 (NROW*VRAW)
    const size_t off_h   = 65536;
    const size_t off_t16 = off_h + (size_t)NROW * VRAW * 4;        // 83,968,000
    const size_t off_tgt = off_t16 + (size_t)VRAW * 8 * 2;          // 84,131,872 (16B aligned)
    const size_t need    = off_tgt + (size_t)NROW * (VRAW / 2) * 4; // ~126 MB

    unsigned short* Wbf = (unsigned short*)d_ws;
    float* h            = (float*)((char*)d_ws + off_h);
    unsigned short* T16 = (unsigned short*)((char*)d_ws + off_t16);
    unsigned* tgt32     = (unsigned*)((char*)d_ws + off_tgt);
    const bool use_tgt  = ws_size >= need;

    convw_kernel<<<COUT * CIN / 256, 256, 0, stream>>>(W, Wbf);
    prep_kernel<<<(VRAW * 8 + 255) / 256, 256, 0, stream>>>(up, down, T16);
    if (use_tgt) {
        dim3 tgrid((VRAW / 2 + 255) / 256, NROW);
        tgt_kernel<<<tgrid, 256, 0, stream>>>(mpi, T16, tgt32);
    }

    dim3 ggrid((VRAW + VT - 1) / VT, NB);
    gemm_kernel<<<ggrid, 256, 0, stream>>>(x, Wbf, bias, h);

    if (use_tgt)
        scatter_kernel<1><<<NROW * 4, 512, 0, stream>>>(tgt32, T16, mpi, h, y);
    else
        scatter_kernel<0><<<NROW * 4, 512, 0, stream>>>(tgt32, T16, mpi, h, y);
}